// Round 2
// baseline (687.311 us; speedup 1.0000x reference)
//
#include <hip/hip_runtime.h>
#include <math.h>

// ElectronicEmbedding (SpookyNet), MI355X.
// Rank-1 structure: v_n = e_b*Wv  =>  y_n = coef_n * Wv, coef_n scalar.
// Whole residual MLP output is a 1-D function G(coef): tabulate + lerp.
// q-GEMM collapses: dot_n = (e/enorm)/16 * (u . x_n + c0), u = Wq^T Wk.
// Defensive: device-side dtype detection (bf16 vs f32 floats, i32 vs i64 seg),
// table sized from ws_size, per-atom scalars stashed in d_out rows.

#define F 256
#define PTS 4

typedef unsigned short u16;
typedef unsigned int u32;

__device__ __forceinline__ float b2f(u16 u) {
    union { u32 i; float f; } v; v.i = ((u32)u) << 16; return v.f;
}
__device__ __forceinline__ u16 f2b(float f) {
    union { float f; u32 i; } v; v.f = f;
    u32 r = 0x7fffu + ((v.i >> 16) & 1u);
    return (u16)((v.i + r) >> 16);
}
__device__ __forceinline__ float silu_(float v) { return v / (1.f + __expf(-v)); }
__device__ __forceinline__ float loadf(const void* p, size_t i, int f32) {
    return f32 ? ((const float*)p)[i] : b2f(((const u16*)p)[i]);
}
__device__ __forceinline__ int loadseg(const int* seg, int n, int i64) {
    return i64 ? seg[2 * n] : seg[n];
}

// K0: detect float dtype (bit0: 1=f32) and seg dtype (bit1: 1=int64)
__global__ __launch_bounds__(256) void k_flag(const u16* __restrict__ x,
                                              const int* __restrict__ seg,
                                              u32* __restrict__ flag) {
    int t = threadIdx.x;
    int weird = 0;
    #pragma unroll
    for (int i = 0; i < 16; ++i) {
        u16 u = x[t * 16 + i];
        u32 e = (u >> 7) & 0xFF;
        weird += (e >= 0xC0) ? 1 : 0;            // |v| >= 2^65: absurd for data
    }
    int zodd = (seg[2 * t + 1] == 0) ? 1 : 0;    // int64 => odd words all zero
    __shared__ int redw[256], redz[256];
    redw[t] = weird; redz[t] = zodd;
    __syncthreads();
    for (int s = 128; s > 0; s >>= 1) {
        if (t < s) { redw[t] += redw[t + s]; redz[t] += redz[t + s]; }
        __syncthreads();
    }
    if (t == 0) flag[0] = ((redw[0] > 64) ? 1u : 0u) | ((redz[0] >= 200) ? 2u : 0u);
}

// K1: uvec[j] = sum_r Wk[r]*Wq[r][j]; uvec[F] = Wk.bq
__global__ __launch_bounds__(256) void k_prep(const void* __restrict__ Wq,
                                              const void* __restrict__ bq,
                                              const void* __restrict__ Wk,
                                              const u32* __restrict__ flag,
                                              float* __restrict__ uvec) {
    int j = threadIdx.x;
    int f32 = (int)(flag[0] & 1u);
    float acc = 0.f;
    for (int f = 0; f < F; ++f)
        acc += loadf(Wk, f, f32) * loadf(Wq, (size_t)f * F + j, f32);
    uvec[j] = acc;
    __shared__ float red[256];
    red[j] = loadf(Wk, j, f32) * loadf(bq, j, f32);
    __syncthreads();
    for (int s = 128; s > 0; s >>= 1) {
        if (j < s) red[j] += red[j + s];
        __syncthreads();
    }
    if (j == 0) uvec[F] = red[0];
}

// K2: per-atom dot -> softplus a; stash a in out-row n; segment-sum anorm
__global__ __launch_bounds__(256) void k_dot(const void* __restrict__ x,
                                             const void* __restrict__ E,
                                             const int* __restrict__ seg,
                                             const u32* __restrict__ flag,
                                             const float* __restrict__ uvec,
                                             char* __restrict__ out,
                                             float* __restrict__ anorm, int N) {
    u32 fl = flag[0];
    int f32 = (int)(fl & 1u), i64 = (int)(fl >> 1);
    int wave = threadIdx.x >> 6, lane = threadIdx.x & 63;
    int n = blockIdx.x * 4 + wave;
    if (n >= N) return;
    float4 uv = *(const float4*)(uvec + lane * 4);
    float x0, x1, x2, x3;
    if (f32) {
        float4 xv = *(const float4*)((const float*)x + (size_t)n * F + lane * 4);
        x0 = xv.x; x1 = xv.y; x2 = xv.z; x3 = xv.w;
    } else {
        uint2 xv = *(const uint2*)((const u16*)x + (size_t)n * F + lane * 4);
        x0 = b2f((u16)(xv.x & 0xffff)); x1 = b2f((u16)(xv.x >> 16));
        x2 = b2f((u16)(xv.y & 0xffff)); x3 = b2f((u16)(xv.y >> 16));
    }
    float s = x0 * uv.x + x1 * uv.y + x2 * uv.z + x3 * uv.w;
    #pragma unroll
    for (int off = 32; off > 0; off >>= 1) s += __shfl_down(s, off, 64);
    if (lane == 0) {
        int b = loadseg(seg, n, i64);
        float e = fabsf(loadf(E, b, f32));
        float dot = (e / fmaxf(e, 1.f)) * (s + uvec[F]) * 0.0625f;
        float a = fmaxf(dot, 0.f) + log1pf(expf(-fabsf(dot)));
        *(float*)(out + (size_t)n * F * (f32 ? 4 : 2)) = a;
        atomicAdd(&anorm[b], a);
    }
}

// K3: coef_n = a*e/(anorm+eps) in-place in out-row; global max(coef)
__global__ __launch_bounds__(256) void k_coef(const void* __restrict__ E,
                                              const int* __restrict__ seg,
                                              const u32* __restrict__ flag,
                                              const float* __restrict__ anorm,
                                              char* __restrict__ out,
                                              u32* __restrict__ cmax, int N) {
    u32 fl = flag[0];
    int f32 = (int)(fl & 1u), i64 = (int)(fl >> 1);
    int n = blockIdx.x * 256 + threadIdx.x;
    float c = 0.f;
    if (n < N) {
        int b = loadseg(seg, n, i64);
        float e = fabsf(loadf(E, b, f32));
        float* p = (float*)(out + (size_t)n * F * (f32 ? 4 : 2));
        c = p[0] * e / (anorm[b] + 1e-8f);
        p[0] = c;
    }
    #pragma unroll
    for (int off = 32; off > 0; off >>= 1) c = fmaxf(c, __shfl_down(c, off, 64));
    if ((threadIdx.x & 63) == 0) atomicMax(cmax, __float_as_uint(c));  // c>=0
}

// K4: tabulate G on mtab points
template <int DT>
__device__ __forceinline__ void matvec(const void* __restrict__ W, size_t off,
                                       const float4* __restrict__ act, float* g) {
    #pragma unroll 4
    for (int f8 = 0; f8 < F; f8 += 8) {
        float w[8];
        if (DT) {
            const float* Wf = (const float*)W + off + f8;
            float4 w0 = *(const float4*)Wf;
            float4 w1 = *(const float4*)(Wf + 4);
            w[0] = w0.x; w[1] = w0.y; w[2] = w0.z; w[3] = w0.w;
            w[4] = w1.x; w[5] = w1.y; w[6] = w1.z; w[7] = w1.w;
        } else {
            uint4 wv = *(const uint4*)((const u16*)W + off + f8);
            w[0] = b2f((u16)(wv.x & 0xffff)); w[1] = b2f((u16)(wv.x >> 16));
            w[2] = b2f((u16)(wv.y & 0xffff)); w[3] = b2f((u16)(wv.y >> 16));
            w[4] = b2f((u16)(wv.z & 0xffff)); w[5] = b2f((u16)(wv.z >> 16));
            w[6] = b2f((u16)(wv.w & 0xffff)); w[7] = b2f((u16)(wv.w >> 16));
        }
        #pragma unroll
        for (int q = 0; q < 8; ++q) {
            float4 a = act[f8 + q];  // same addr all threads -> LDS broadcast
            g[0] += a.x * w[q]; g[1] += a.y * w[q];
            g[2] += a.z * w[q]; g[3] += a.w * w[q];
        }
    }
}

template <int DT>
__device__ void table_body(const void* Wv, const void* W1, const void* W2,
                           const void* Wo, float cmax, float* table, int R, int mtab) {
    int j = threadIdx.x;
    int i0 = blockIdx.x * PTS;
    __shared__ float4 actA[F];
    __shared__ float4 actB[F];
    float h[PTS], g[PTS];
    float wvj = loadf(Wv, j, DT);
    #pragma unroll
    for (int p = 0; p < PTS; ++p)
        h[p] = cmax * ((float)(i0 + p) / (float)(mtab - 1)) * wvj;
    for (int r = 0; r < R; ++r) {
        size_t o = (size_t)r * F * F + (size_t)j * F;
        actA[j] = make_float4(silu_(h[0]), silu_(h[1]), silu_(h[2]), silu_(h[3]));
        __syncthreads();
        #pragma unroll
        for (int p = 0; p < PTS; ++p) g[p] = 0.f;
        matvec<DT>(W1, o, actA, g);
        actB[j] = make_float4(silu_(g[0]), silu_(g[1]), silu_(g[2]), silu_(g[3]));
        __syncthreads();
        matvec<DT>(W2, o, actB, h);  // h += (residual)
        __syncthreads();
    }
    actA[j] = make_float4(silu_(h[0]), silu_(h[1]), silu_(h[2]), silu_(h[3]));
    __syncthreads();
    #pragma unroll
    for (int p = 0; p < PTS; ++p) g[p] = 0.f;
    matvec<DT>(Wo, (size_t)j * F, actA, g);
    #pragma unroll
    for (int p = 0; p < PTS; ++p) table[(size_t)(i0 + p) * F + j] = g[p];
}

__global__ __launch_bounds__(256) void k_table(const void* Wv, const void* W1,
                                               const void* W2, const void* Wo,
                                               const u32* __restrict__ flag,
                                               const u32* __restrict__ cmaxu,
                                               float* __restrict__ table, int R, int mtab) {
    float cmax = __uint_as_float(cmaxu[0]);
    if (flag[0] & 1u) table_body<1>(Wv, W1, W2, Wo, cmax, table, R, mtab);
    else              table_body<0>(Wv, W1, W2, Wo, cmax, table, R, mtab);
}

// K5: out row n = lerp(table, coef_n)
__global__ __launch_bounds__(256) void k_out(const u32* __restrict__ flag,
                                             const float* __restrict__ table,
                                             const u32* __restrict__ cmaxu,
                                             char* __restrict__ out, int N, int mtab) {
    int f32 = (int)(flag[0] & 1u);
    int t = blockIdx.x * 256 + threadIdx.x;
    int n = t >> 6, lane = t & 63;
    if (n >= N) return;
    float cmax = __uint_as_float(cmaxu[0]);
    size_t rowb = (size_t)n * F * (f32 ? 4 : 2);
    float c = *(const float*)(out + rowb);  // read precedes lane-0 overwrite
    float pos = (cmax > 0.f) ? (c / cmax) * (float)(mtab - 1) : 0.f;
    pos = fminf(fmaxf(pos, 0.f), (float)(mtab - 1));
    int idx = (int)pos;
    if (idx > mtab - 2) idx = mtab - 2;
    float fr = pos - (float)idx;
    const float4 t0 = *(const float4*)(table + (size_t)idx * F + lane * 4);
    const float4 t1 = *(const float4*)(table + (size_t)(idx + 1) * F + lane * 4);
    float o0 = t0.x + fr * (t1.x - t0.x);
    float o1 = t0.y + fr * (t1.y - t0.y);
    float o2 = t0.z + fr * (t1.z - t0.z);
    float o3 = t0.w + fr * (t1.w - t0.w);
    if (f32) {
        *(float4*)(out + rowb + (size_t)lane * 16) = make_float4(o0, o1, o2, o3);
    } else {
        u32 lo = (u32)f2b(o0) | ((u32)f2b(o1) << 16);
        u32 hi = (u32)f2b(o2) | ((u32)f2b(o3) << 16);
        *(uint2*)(out + rowb + (size_t)lane * 8) = make_uint2(lo, hi);
    }
}

extern "C" void kernel_launch(void* const* d_in, const int* in_sizes, int n_in,
                              void* d_out, int out_size, void* d_ws, size_t ws_size,
                              hipStream_t stream) {
    // If the scalar num_batch was dropped from d_in, indices shift by one.
    int si = (in_sizes[2] == 1) ? 3 : 2;  // index of batch_seg
    const void* x   = d_in[0];
    const void* E   = d_in[1];
    const int* seg  = (const int*)d_in[si];
    const void* Wq  = d_in[si + 1];
    const void* bq  = d_in[si + 2];
    const void* Wk  = d_in[si + 3];
    const void* Wv  = d_in[si + 4];
    const void* W1  = d_in[si + 5];
    const void* W2  = d_in[si + 6];
    const void* Wo  = d_in[si + 7];

    const int B = in_sizes[1];
    const int N = in_sizes[0] / F;
    const int R = in_sizes[si + 5] / (F * F);

    float* ws    = (float*)d_ws;
    float* uvec  = ws;                   // [0..257)
    u32*   cmaxu = (u32*)ws + 258;
    u32*   flag  = (u32*)ws + 259;
    float* anorm = ws + 512;             // B floats
    float* table = ws + 4096;            // mtab*F floats

    size_t avail = (ws_size > 4096 * 4) ? ws_size - 4096 * 4 : 0;
    int mtab = 2048;
    while (mtab > 32 && (size_t)mtab * F * sizeof(float) > avail) mtab >>= 1;

    hipMemsetAsync(cmaxu, 0, 4, stream);
    hipMemsetAsync(anorm, 0, (size_t)B * sizeof(float), stream);
    k_flag<<<1, 256, 0, stream>>>((const u16*)x, seg, flag);
    k_prep<<<1, 256, 0, stream>>>(Wq, bq, Wk, flag, uvec);
    k_dot<<<(N + 3) / 4, 256, 0, stream>>>(x, E, seg, flag, uvec, (char*)d_out, anorm, N);
    k_coef<<<(N + 255) / 256, 256, 0, stream>>>(E, seg, flag, anorm, (char*)d_out, cmaxu, N);
    k_table<<<mtab / PTS, 256, 0, stream>>>(Wv, W1, W2, Wo, flag, cmaxu, table, R, mtab);
    k_out<<<(N * 64 + 255) / 256, 256, 0, stream>>>(flag, table, cmaxu, (char*)d_out, N, mtab);
}

// Round 3
// 502.681 us; speedup vs baseline: 1.3673x; 1.3673x over previous
//
#include <hip/hip_runtime.h>
#include <math.h>

// ElectronicEmbedding (SpookyNet), MI355X.
// Rank-1: y_n = coef_n * Wv (scalar per atom) => MLP output is 1-D G(coef);
// tabulate G (mtab pts) + lerp. dot_n = (e/enorm)/16 * (u.x_n + c0), u=Wq^T Wk.
// R3: bandwidth restructure. Quarter-wave per row, 16 rows/wave-iter (8 deep
// 16B loads/lane), segmented wave-combined atomics over sorted seg, coef pass
// fused into k_out, cmax from per-batch amax.

#define F 256
#define PTS 4
#define GRP 16

typedef unsigned short u16;
typedef unsigned int u32;

__device__ __forceinline__ float b2f(u16 u) {
    union { u32 i; float f; } v; v.i = ((u32)u) << 16; return v.f;
}
__device__ __forceinline__ u16 f2b(float f) {
    union { float f; u32 i; } v; v.f = f;
    u32 r = 0x7fffu + ((v.i >> 16) & 1u);
    return (u16)((v.i + r) >> 16);
}
__device__ __forceinline__ float silu_(float v) { return v / (1.f + __expf(-v)); }
__device__ __forceinline__ float loadf(const void* p, size_t i, int f32) {
    return f32 ? ((const float*)p)[i] : b2f(((const u16*)p)[i]);
}
__device__ __forceinline__ int loadseg(const int* seg, int n, int i64) {
    return i64 ? seg[2 * n] : seg[n];
}

// K0: detect float dtype (bit0: 1=f32) and seg dtype (bit1: 1=int64)
__global__ __launch_bounds__(256) void k_flag(const u16* __restrict__ x,
                                              const int* __restrict__ seg,
                                              u32* __restrict__ flag) {
    int t = threadIdx.x;
    int weird = 0;
    #pragma unroll
    for (int i = 0; i < 16; ++i) {
        u16 u = x[t * 16 + i];
        u32 e = (u >> 7) & 0xFF;
        weird += (e >= 0xC0) ? 1 : 0;
    }
    int zodd = (seg[2 * t + 1] == 0) ? 1 : 0;
    __shared__ int redw[256], redz[256];
    redw[t] = weird; redz[t] = zodd;
    __syncthreads();
    for (int s = 128; s > 0; s >>= 1) {
        if (t < s) { redw[t] += redw[t + s]; redz[t] += redz[t + s]; }
        __syncthreads();
    }
    if (t == 0) flag[0] = ((redw[0] > 64) ? 1u : 0u) | ((redz[0] >= 200) ? 2u : 0u);
}

// K1: uvec[j] += sum_{f in my 8} Wk[f]*Wq[f][j]; block 0 adds uvec[F]=Wk.bq
__global__ __launch_bounds__(256) void k_prep(const void* __restrict__ Wq,
                                              const void* __restrict__ bq,
                                              const void* __restrict__ Wk,
                                              const u32* __restrict__ flag,
                                              float* __restrict__ uvec) {
    int j = threadIdx.x;
    int f32 = (int)(flag[0] & 1u);
    int f0 = blockIdx.x * 8;
    float acc = 0.f;
    for (int f = f0; f < f0 + 8; ++f)
        acc += loadf(Wk, f, f32) * loadf(Wq, (size_t)f * F + j, f32);
    atomicAdd(&uvec[j], acc);
    if (blockIdx.x == 0) {
        __shared__ float red[256];
        red[j] = loadf(Wk, j, f32) * loadf(bq, j, f32);
        __syncthreads();
        for (int s = 128; s > 0; s >>= 1) {
            if (j < s) red[j] += red[j + s];
            __syncthreads();
        }
        if (j == 0) uvec[F] = red[0];
    }
}

// K2: dot + softplus a (stashed in out row), segmented atomics anorm/amax
template <int DT>
__device__ void dot_body(const char* __restrict__ x, const void* __restrict__ E,
                         const int* __restrict__ seg, int i64,
                         const float* __restrict__ uvec, char* __restrict__ out,
                         float* __restrict__ anorm, u32* __restrict__ amax, int N) {
    const int lane = threadIdx.x & 63;
    const int q = lane & 3, g = lane >> 2;
    const int wid = (blockIdx.x * blockDim.x + threadIdx.x) >> 6;
    const int nw = (gridDim.x * blockDim.x) >> 6;
    const int ngrp = (N + GRP - 1) / GRP;
    const int NL = DT ? 16 : 8;          // 16B loads per lane per row
    float uf[64];
    #pragma unroll
    for (int i = 0; i < 16; ++i) {
        if (i >= NL) break;
        if (DT) {
            *(float4*)&uf[i * 4] = *(const float4*)(uvec + (q + 4 * i) * 4);
        } else {
            int eo = (q + 4 * i) * 8;
            *(float4*)&uf[i * 8]     = *(const float4*)(uvec + eo);
            *(float4*)&uf[i * 8 + 4] = *(const float4*)(uvec + eo + 4);
        }
    }
    const float c0 = uvec[F];
    const size_t rowbytes = (size_t)F * (DT ? 4 : 2);
    for (int grp = wid; grp < ngrp; grp += nw) {
        const int row = grp * GRP + g;
        float s = 0.f;
        if (row < N) {
            const char* rp = x + (size_t)row * rowbytes;
            if (DT) {
                #pragma unroll
                for (int i = 0; i < 16; ++i) {
                    float4 v = *(const float4*)(rp + (size_t)(q + 4 * i) * 16);
                    s += v.x * uf[i*4] + v.y * uf[i*4+1] + v.z * uf[i*4+2] + v.w * uf[i*4+3];
                }
            } else {
                #pragma unroll
                for (int i = 0; i < 8; ++i) {
                    uint4 v = *(const uint4*)(rp + (size_t)(q + 4 * i) * 16);
                    const u32 w[4] = {v.x, v.y, v.z, v.w};
                    #pragma unroll
                    for (int k = 0; k < 4; ++k) {
                        s += b2f((u16)(w[k] & 0xffff)) * uf[i*8 + 2*k];
                        s += b2f((u16)(w[k] >> 16))    * uf[i*8 + 2*k + 1];
                    }
                }
            }
        }
        s += __shfl_xor(s, 1, 64);
        s += __shfl_xor(s, 2, 64);
        float a = 0.f; int b = 0x7fffffff;
        if (q == 0 && row < N) {
            b = loadseg(seg, row, i64);
            float e = fabsf(loadf(E, b, DT));
            float dot = (e / fmaxf(e, 1.f)) * (s + c0) * 0.0625f;
            a = fmaxf(dot, 0.f) + log1pf(expf(-fabsf(dot)));
            *(float*)(out + (size_t)row * rowbytes) = a;   // stash for k_out
        }
        // segmented suffix-combine across owner lanes (seg sorted)
        float rs = a, rm = a;
        #pragma unroll
        for (int off = 4; off <= 32; off <<= 1) {
            float rs2 = __shfl_down(rs, off, 64);
            float rm2 = __shfl_down(rm, off, 64);
            int   b2  = __shfl_down(b, off, 64);
            if (lane + off < 64 && b2 == b) { rs += rs2; rm = fmaxf(rm, rm2); }
        }
        int bprev = __shfl_up(b, 4, 64);
        if (q == 0 && row < N && (g == 0 || bprev != b)) {
            atomicAdd(&anorm[b], rs);
            atomicMax(&amax[b], __float_as_uint(rm));   // a >= 0
        }
    }
}

__global__ __launch_bounds__(256) void k_dot(const void* x, const void* E,
                                             const int* seg, const u32* flag,
                                             const float* uvec, void* out,
                                             float* anorm, u32* amax, int N) {
    u32 fl = flag[0];
    if (fl & 1u) dot_body<1>((const char*)x, E, seg, (int)(fl >> 1), uvec, (char*)out, anorm, amax, N);
    else         dot_body<0>((const char*)x, E, seg, (int)(fl >> 1), uvec, (char*)out, anorm, amax, N);
}

// K3: cmax = max_b amax_b * e_b / (anorm_b + eps)   (exact per-batch max coef)
__global__ __launch_bounds__(256) void k_bmax(const void* __restrict__ E,
                                              const u32* __restrict__ flag,
                                              const float* __restrict__ anorm,
                                              const u32* __restrict__ amax,
                                              u32* __restrict__ cmax, int B) {
    int f32 = (int)(flag[0] & 1u);
    float m = 0.f;
    for (int b = blockIdx.x * 256 + threadIdx.x; b < B; b += gridDim.x * 256)
        m = fmaxf(m, __uint_as_float(amax[b]) * fabsf(loadf(E, b, f32)) / (anorm[b] + 1e-8f));
    #pragma unroll
    for (int off = 32; off > 0; off >>= 1) m = fmaxf(m, __shfl_down(m, off, 64));
    if ((threadIdx.x & 63) == 0) atomicMax(cmax, __float_as_uint(m));
}

// K4: tabulate G on mtab points
template <int DT>
__device__ __forceinline__ void matvec(const void* __restrict__ W, size_t off,
                                       const float4* __restrict__ act, float* g) {
    #pragma unroll 4
    for (int f8 = 0; f8 < F; f8 += 8) {
        float w[8];
        if (DT) {
            const float* Wf = (const float*)W + off + f8;
            float4 w0 = *(const float4*)Wf;
            float4 w1 = *(const float4*)(Wf + 4);
            w[0] = w0.x; w[1] = w0.y; w[2] = w0.z; w[3] = w0.w;
            w[4] = w1.x; w[5] = w1.y; w[6] = w1.z; w[7] = w1.w;
        } else {
            uint4 wv = *(const uint4*)((const u16*)W + off + f8);
            w[0] = b2f((u16)(wv.x & 0xffff)); w[1] = b2f((u16)(wv.x >> 16));
            w[2] = b2f((u16)(wv.y & 0xffff)); w[3] = b2f((u16)(wv.y >> 16));
            w[4] = b2f((u16)(wv.z & 0xffff)); w[5] = b2f((u16)(wv.z >> 16));
            w[6] = b2f((u16)(wv.w & 0xffff)); w[7] = b2f((u16)(wv.w >> 16));
        }
        #pragma unroll
        for (int q = 0; q < 8; ++q) {
            float4 a = act[f8 + q];
            g[0] += a.x * w[q]; g[1] += a.y * w[q];
            g[2] += a.z * w[q]; g[3] += a.w * w[q];
        }
    }
}

template <int DT>
__device__ void table_body(const void* Wv, const void* W1, const void* W2,
                           const void* Wo, float cmax, float* table, int R, int mtab) {
    int j = threadIdx.x;
    int i0 = blockIdx.x * PTS;
    __shared__ float4 actA[F];
    __shared__ float4 actB[F];
    float h[PTS], g[PTS];
    float wvj = loadf(Wv, j, DT);
    #pragma unroll
    for (int p = 0; p < PTS; ++p)
        h[p] = cmax * ((float)(i0 + p) / (float)(mtab - 1)) * wvj;
    for (int r = 0; r < R; ++r) {
        size_t o = (size_t)r * F * F + (size_t)j * F;
        actA[j] = make_float4(silu_(h[0]), silu_(h[1]), silu_(h[2]), silu_(h[3]));
        __syncthreads();
        #pragma unroll
        for (int p = 0; p < PTS; ++p) g[p] = 0.f;
        matvec<DT>(W1, o, actA, g);
        actB[j] = make_float4(silu_(g[0]), silu_(g[1]), silu_(g[2]), silu_(g[3]));
        __syncthreads();
        matvec<DT>(W2, o, actB, h);
        __syncthreads();
    }
    actA[j] = make_float4(silu_(h[0]), silu_(h[1]), silu_(h[2]), silu_(h[3]));
    __syncthreads();
    #pragma unroll
    for (int p = 0; p < PTS; ++p) g[p] = 0.f;
    matvec<DT>(Wo, (size_t)j * F, actA, g);
    #pragma unroll
    for (int p = 0; p < PTS; ++p) table[(size_t)(i0 + p) * F + j] = g[p];
}

__global__ __launch_bounds__(256) void k_table(const void* Wv, const void* W1,
                                               const void* W2, const void* Wo,
                                               const u32* __restrict__ flag,
                                               const u32* __restrict__ cmaxu,
                                               float* __restrict__ table, int R, int mtab) {
    float cmax = __uint_as_float(cmaxu[0]);
    if (flag[0] & 1u) table_body<1>(Wv, W1, W2, Wo, cmax, table, R, mtab);
    else              table_body<0>(Wv, W1, W2, Wo, cmax, table, R, mtab);
}

// K5: coef from stashed a (fused), lerp table, write full rows
template <int DT>
__device__ void out_body(const void* __restrict__ E, const int* __restrict__ seg,
                         int i64, const float* __restrict__ anorm,
                         const float* __restrict__ table, float cmax,
                         char* __restrict__ out, int N, int mtab) {
    const int lane = threadIdx.x & 63;
    const int q = lane & 3, g = lane >> 2;
    const int wid = (blockIdx.x * blockDim.x + threadIdx.x) >> 6;
    const int nw = (gridDim.x * blockDim.x) >> 6;
    const int ngrp = (N + GRP - 1) / GRP;
    const size_t rowbytes = (size_t)F * (DT ? 4 : 2);
    for (int grp = wid; grp < ngrp; grp += nw) {
        const int row = grp * GRP + g;
        if (row >= N) continue;
        char* rp = out + (size_t)row * rowbytes;
        float a = *(const float*)rp;                  // stash (load precedes store)
        int b = loadseg(seg, row, i64);
        float e = fabsf(loadf(E, b, DT));
        float c = a * e / (anorm[b] + 1e-8f);
        float pos = (cmax > 0.f) ? (c / cmax) * (float)(mtab - 1) : 0.f;
        pos = fminf(fmaxf(pos, 0.f), (float)(mtab - 1));
        int idx = (int)pos;
        if (idx > mtab - 2) idx = mtab - 2;
        float fr = pos - (float)idx;
        const float* t0 = table + (size_t)idx * F;
        const float* t1 = t0 + F;
        if (DT) {
            #pragma unroll
            for (int i = 0; i < 16; ++i) {
                int eo = (q + 4 * i) * 4;
                float4 u0 = *(const float4*)(t0 + eo);
                float4 u1 = *(const float4*)(t1 + eo);
                float4 o;
                o.x = u0.x + fr * (u1.x - u0.x);
                o.y = u0.y + fr * (u1.y - u0.y);
                o.z = u0.z + fr * (u1.z - u0.z);
                o.w = u0.w + fr * (u1.w - u0.w);
                *(float4*)(rp + (size_t)eo * 4) = o;
            }
        } else {
            #pragma unroll
            for (int i = 0; i < 8; ++i) {
                int eo = (q + 4 * i) * 8;
                float4 u0 = *(const float4*)(t0 + eo);
                float4 u1 = *(const float4*)(t1 + eo);
                float4 v0 = *(const float4*)(t0 + eo + 4);
                float4 v1 = *(const float4*)(t1 + eo + 4);
                uint4 ov;
                ov.x = (u32)f2b(u0.x + fr * (u1.x - u0.x)) | ((u32)f2b(u0.y + fr * (u1.y - u0.y)) << 16);
                ov.y = (u32)f2b(u0.z + fr * (u1.z - u0.z)) | ((u32)f2b(u0.w + fr * (u1.w - u0.w)) << 16);
                ov.z = (u32)f2b(v0.x + fr * (v1.x - v0.x)) | ((u32)f2b(v0.y + fr * (v1.y - v0.y)) << 16);
                ov.w = (u32)f2b(v0.z + fr * (v1.z - v0.z)) | ((u32)f2b(v0.w + fr * (v1.w - v0.w)) << 16);
                *(uint4*)(rp + (size_t)eo * 2) = ov;
            }
        }
    }
}

__global__ __launch_bounds__(256) void k_out(const void* E, const int* seg,
                                             const u32* flag, const float* anorm,
                                             const float* table, const u32* cmaxu,
                                             void* out, int N, int mtab) {
    u32 fl = flag[0];
    float cmax = __uint_as_float(cmaxu[0]);
    if (fl & 1u) out_body<1>(E, seg, (int)(fl >> 1), anorm, table, cmax, (char*)out, N, mtab);
    else         out_body<0>(E, seg, (int)(fl >> 1), anorm, table, cmax, (char*)out, N, mtab);
}

extern "C" void kernel_launch(void* const* d_in, const int* in_sizes, int n_in,
                              void* d_out, int out_size, void* d_ws, size_t ws_size,
                              hipStream_t stream) {
    int si = (in_sizes[2] == 1) ? 3 : 2;  // batch_seg index (scalar may be dropped)
    const void* x   = d_in[0];
    const void* E   = d_in[1];
    const int* seg  = (const int*)d_in[si];
    const void* Wq  = d_in[si + 1];
    const void* bq  = d_in[si + 2];
    const void* Wk  = d_in[si + 3];
    const void* Wv  = d_in[si + 4];
    const void* W1  = d_in[si + 5];
    const void* W2  = d_in[si + 6];
    const void* Wo  = d_in[si + 7];

    const int B = in_sizes[1];
    const int N = in_sizes[0] / F;
    const int R = in_sizes[si + 5] / (F * F);

    float* ws    = (float*)d_ws;
    float* uvec  = ws;                    // [0..257)
    u32*   cmaxu = (u32*)ws + 258;
    u32*   flag  = (u32*)ws + 259;
    float* anorm = ws + 512;              // B floats
    u32*   amax  = (u32*)ws + 512 + B;    // B u32
    size_t tof   = (size_t)(512 + 2 * B + 64);
    if (tof < 8192) tof = 8192;
    float* table = ws + tof;

    size_t avail = (ws_size > tof * 4) ? ws_size - tof * 4 : 0;
    int mtab = 2048;
    while (mtab > 32 && (size_t)mtab * F * sizeof(float) > avail) mtab >>= 1;

    hipMemsetAsync(ws, 0, tof * 4, stream);  // zeroes uvec, cmax, flag, anorm, amax
    k_flag<<<1, 256, 0, stream>>>((const u16*)x, seg, flag);
    k_prep<<<32, 256, 0, stream>>>(Wq, bq, Wk, flag, uvec);
    const int ngrp = (N + GRP - 1) / GRP;
    int blocks = (ngrp + 3) / 4; if (blocks > 1024) blocks = 1024;
    k_dot<<<blocks, 256, 0, stream>>>(x, E, seg, flag, uvec, d_out, anorm, amax, N);
    k_bmax<<<8, 256, 0, stream>>>(E, flag, anorm, amax, cmaxu, B);
    k_table<<<mtab / PTS, 256, 0, stream>>>(Wv, W1, W2, Wo, flag, cmaxu, table, R, mtab);
    k_out<<<blocks, 256, 0, stream>>>(E, seg, flag, anorm, table, cmaxu, d_out, N, mtab);
}